// Round 6
// baseline (1136.423 us; speedup 1.0000x reference)
//
#include <hip/hip_runtime.h>
#include <hip/hip_bf16.h>
#include <math.h>

#define TT 512   // T
#define BB 128   // B
#define EE 100   // embed dim
#define HH 128   // hidden
#define G4 512   // 4*H
#define K1 256   // 2*H

typedef __attribute__((ext_vector_type(8))) short bf16x8;
typedef __attribute__((ext_vector_type(4))) float f32x4;

__device__ inline void split2(float v, unsigned short& hi, unsigned short& lo) {
    __hip_bfloat16 h = __float2bfloat16(v);
    float hf = __bfloat162float(h);
    __hip_bfloat16 l = __float2bfloat16(v - hf);
    hi = *reinterpret_cast<unsigned short*>(&h);
    lo = *reinterpret_cast<unsigned short*>(&l);
}

__device__ inline void gload16(const void* g, void* l) {
    __builtin_amdgcn_global_load_lds(
        (const __attribute__((address_space(1))) void*)g,
        (__attribute__((address_space(3))) void*)l, 16, 0, 0);
}

// ---- embedding -> xs2 bf16 [hi(128) | lo(128)] per (t,b) row ---------------
__global__ void embed_cvt(const int* __restrict__ x, const float* __restrict__ emb,
                          unsigned short* __restrict__ xs2) {
    int row = blockIdx.x;          // t*B + b
    int k = threadIdx.x;           // 0..127
    int b = row & 127, t = row >> 7;
    int tok = x[b * TT + t];
    float v = (k < EE) ? emb[(size_t)tok * EE + k] : 0.f;
    unsigned short hi, lo;
    split2(v, hi, lo);
    xs2[(size_t)row * 256 + k] = hi;
    xs2[(size_t)row * 256 + 128 + k] = lo;
}

// ---- weight -> bf16 [hi(Kp)|lo(Kp)], rows PERMUTED to unit-major ----------
// dst row n' <- src row ((n'&3)<<7)|(n'>>2)  (so C col n' = gate n'&3 of unit n'>>2)
__global__ void wcvt(const float* __restrict__ src, int Kin, int Kp,
                     unsigned short* __restrict__ dst) {
    int n = blockIdx.x;            // 0..511 (dst row)
    int k = threadIdx.x;           // 0..Kp-1
    int r = ((n & 3) << 7) | (n >> 2);
    float v = (k < Kin) ? src[(size_t)r * Kin + k] : 0.f;
    unsigned short hi, lo;
    split2(v, hi, lo);
    dst[(size_t)n * 2 * Kp + k] = hi;
    dst[(size_t)n * 2 * Kp + Kp + k] = lo;
}

// ---- bias: dst[dir*512+n] = bih[perm(n)] + bhh[perm(n)] -------------------
__global__ void bias_cat(const float* __restrict__ bihf, const float* __restrict__ bhhf,
                         const float* __restrict__ bihr, const float* __restrict__ bhhr,
                         float* __restrict__ dst) {
    int n = blockIdx.x * 256 + threadIdx.x;   // 0..1023
    int d = n >> 9, m = n & 511;
    int src = ((m & 3) << 7) | (m >> 2);
    const float* a = d ? bihr : bihf;
    const float* c = d ? bhhr : bhhf;
    dst[n] = a[src] + c[src];
}

// ---- pack whh -> wpk[u][k][gate] (float4 per (u,k)) -----------------------
__global__ void whh_pack(const float* __restrict__ whh, float* __restrict__ dst) {
    int u = blockIdx.x;            // 0..127
    int k = threadIdx.x;           // 0..127
    float4 v;
    v.x = whh[((size_t)(0 * 128 + u)) * 128 + k];
    v.y = whh[((size_t)(1 * 128 + u)) * 128 + k];
    v.z = whh[((size_t)(2 * 128 + u)) * 128 + k];
    v.w = whh[((size_t)(3 * 128 + u)) * 128 + k];
    reinterpret_cast<float4*>(dst)[(size_t)u * 128 + k] = v;
}

// ---- merged MFMA GEMM (fwd+bwd): grid (8, TC) -----------------------------
template<int K2>
__global__ __launch_bounds__(256) void gemm_mfma(
    const unsigned short* __restrict__ A2,
    const unsigned short* __restrict__ W2cat,
    const float* __restrict__ biascat,     // (1024,) permuted, bih+bhh
    float* __restrict__ Cf, float* __restrict__ Cr,
    int t_base)
{
    __shared__ bf16x8 As[1024];   // 128 rows x 128 B (64 bf16), swizzled
    __shared__ bf16x8 Bs[1024];
    int tid = threadIdx.x;
    int s = blockIdx.y;
    int dir = blockIdx.x >> 2;
    int nBase = (blockIdx.x & 3) * 128;
    int t = dir ? (TT - 1 - t_base - s) : (t_base + s);
    float* C = dir ? Cr : Cf;
    const unsigned short* Abase = A2 + (size_t)t * BB * K2;
    const unsigned short* Wbase = W2cat + (size_t)(dir * 512 + nBase) * K2;
    int lane = tid & 63, wid = tid >> 6;
    int wr = wid >> 1, wc = wid & 1;
    int l15 = lane & 15, g = lane >> 4;

    f32x4 acc[4][4];
    const f32x4 z = {0.f, 0.f, 0.f, 0.f};
    #pragma unroll
    for (int i = 0; i < 4; ++i)
        #pragma unroll
        for (int j = 0; j < 4; ++j) acc[i][j] = z;

    for (int kt = 0; kt < K2 / 64; ++kt) {
        #pragma unroll
        for (int j = 0; j < 4; ++j) {
            int p = tid + j * 256;
            int row = p >> 3;
            int k16 = (p & 7) ^ (row & 7);   // pre-swizzled source chunk
            size_t goff = (size_t)row * K2 + kt * 64 + k16 * 8;
            gload16(Abase + goff, &As[p]);
            gload16(Wbase + goff, &Bs[p]);
        }
        __syncthreads();
        #pragma unroll
        for (int ks = 0; ks < 2; ++ks) {
            bf16x8 af[4], bfr[4];
            #pragma unroll
            for (int i = 0; i < 4; ++i) {
                int arow = wr * 64 + i * 16 + l15;
                int abyte = arow * 128 + ((ks * 64 + g * 16) ^ ((arow & 7) << 4));
                af[i] = As[abyte >> 4];
                int brow = wc * 64 + i * 16 + l15;
                int bbyte = brow * 128 + ((ks * 64 + g * 16) ^ ((brow & 7) << 4));
                bfr[i] = Bs[bbyte >> 4];
            }
            #pragma unroll
            for (int i = 0; i < 4; ++i)
                #pragma unroll
                for (int j = 0; j < 4; ++j)
                    acc[i][j] = __builtin_amdgcn_mfma_f32_16x16x32_bf16(
                        af[i], bfr[j], acc[i][j], 0, 0, 0);
        }
        __syncthreads();
    }
    #pragma unroll
    for (int i = 0; i < 4; ++i) {
        size_t crow0 = (size_t)s * 128 + wr * 64 + i * 16 + g * 4;
        #pragma unroll
        for (int j = 0; j < 4; ++j) {
            int col = nBase + wc * 64 + j * 16 + l15;
            float bsum = biascat[dir * 512 + col];
            #pragma unroll
            for (int r = 0; r < 4; ++r)
                C[(crow0 + r) * G4 + col] = acc[i][j][r] + bsum;
        }
    }
}

__device__ inline float sig_fast(float z) {
    return __builtin_amdgcn_rcpf(1.f + __expf(-z));
}

// ---- LSTM recurrence: one block per (dir, b); 512 thr; quad-per-unit ------
// thread (u = tid>>2, q = tid&3): K-slice [32q,32q+32) of all 4 gate rows of
// unit u. Weights in 32 NAMED f32x4 registers (wpk[u][k][gate] packed tensor).
// Lane q computes activation of gate q only; quad-share via 3 shfl_xor.
__global__ __launch_bounds__(512, 2) void lstm_chunk(
    const float* __restrict__ gxf,        // (TC*B, 512) unit-major, fwd order
    const float* __restrict__ gxr,        // (TC*B, 512) unit-major, bwd order
    const float* __restrict__ wpkf,       // (128,128,4) packed whh fwd
    const float* __restrict__ wpkr,       // (128,128,4) packed whh bwd
    float* __restrict__ h_state,          // (2, B, 128)
    float* __restrict__ c_state,          // (2, B, 128)
    unsigned short* __restrict__ out_x1,  // x1_2 (T*B,512) bf16 [hi|lo], or null
    int t_base, int TC)
{
    int blk = blockIdx.x;
    int dir = blk >> 7;
    int b   = blk & 127;
    const float* gx  = dir ? gxr : gxf;
    const float* wpk = dir ? wpkr : wpkf;
    int tid = threadIdx.x;
    int u = tid >> 2, q = tid & 3;

    // 32 named f32x4 weight registers: w_i = gates(i,f,g,o) at k = q*32+i
    const f32x4* wp4 = reinterpret_cast<const f32x4*>(wpk) + ((size_t)u * 128 + q * 32);
#define LW(i) const f32x4 w##i = wp4[i];
    LW(0)  LW(1)  LW(2)  LW(3)  LW(4)  LW(5)  LW(6)  LW(7)
    LW(8)  LW(9)  LW(10) LW(11) LW(12) LW(13) LW(14) LW(15)
    LW(16) LW(17) LW(18) LW(19) LW(20) LW(21) LW(22) LW(23)
    LW(24) LW(25) LW(26) LW(27) LW(28) LW(29) LW(30) LW(31)
#undef LW

    // ping-pong h buffer: quarter q at float offset 40q (bank-shifted, 16B-aligned)
    __shared__ float hb[2][160];
    int sbase = (dir * BB + b) * HH;
    int hslot = (u >> 5) * 40 + (u & 31);
    float c = c_state[sbase + u];
    float h = 0.f;
    if (q == 0) hb[0][hslot] = h_state[sbase + u];
    __syncthreads();

    float4 gin4 = *reinterpret_cast<const float4*>(gx + ((size_t)0 * BB + b) * G4 + 4 * u);
    bool q0 = (q == 0), q1 = (q == 1), q2 = (q == 2);
    float fq = q2 ? 2.f : 1.f;
    float bq = q2 ? -1.f : 0.f;

    for (int s = 0; s < TC; ++s) {
        int p = s & 1;
        int sn = (s + 1 < TC) ? s + 1 : s;
        float4 gin4n = *reinterpret_cast<const float4*>(
            gx + ((size_t)sn * BB + b) * G4 + 4 * u);

        const float4* hb4 = reinterpret_cast<const float4*>(&hb[p][40 * q]);
        float4 hv0 = hb4[0], hv1 = hb4[1], hv2 = hb4[2], hv3 = hb4[3];
        float4 hv4 = hb4[4], hv5 = hb4[5], hv6 = hb4[6], hv7 = hb4[7];

        f32x4 a0 = {0.f,0.f,0.f,0.f}, a1 = {0.f,0.f,0.f,0.f};
        f32x4 a2 = {0.f,0.f,0.f,0.f}, a3 = {0.f,0.f,0.f,0.f};
#define FM(i0,i1,i2,i3,HV) { \
        f32x4 hh; \
        hh = f32x4{HV.x,HV.x,HV.x,HV.x}; a0 = __builtin_elementwise_fma(w##i0, hh, a0); \
        hh = f32x4{HV.y,HV.y,HV.y,HV.y}; a1 = __builtin_elementwise_fma(w##i1, hh, a1); \
        hh = f32x4{HV.z,HV.z,HV.z,HV.z}; a2 = __builtin_elementwise_fma(w##i2, hh, a2); \
        hh = f32x4{HV.w,HV.w,HV.w,HV.w}; a3 = __builtin_elementwise_fma(w##i3, hh, a3); }
        FM(0,1,2,3,hv0)    FM(4,5,6,7,hv1)    FM(8,9,10,11,hv2)  FM(12,13,14,15,hv3)
        FM(16,17,18,19,hv4) FM(20,21,22,23,hv5) FM(24,25,26,27,hv6) FM(28,29,30,31,hv7)
#undef FM
        f32x4 acc = (a0 + a1) + (a2 + a3);

        // quad butterfly: sum k-slices across the 4 lanes (all 4 gate comps)
        f32x4 tv;
        tv.x = __shfl_xor(acc.x, 1); tv.y = __shfl_xor(acc.y, 1);
        tv.z = __shfl_xor(acc.z, 1); tv.w = __shfl_xor(acc.w, 1);
        acc += tv;
        tv.x = __shfl_xor(acc.x, 2); tv.y = __shfl_xor(acc.y, 2);
        tv.z = __shfl_xor(acc.z, 2); tv.w = __shfl_xor(acc.w, 2);
        acc += tv;

        // lane q activates gate q (i,f,g,o = comps 0..3), then quad-share
        float pre = (q0 ? acc.x : q1 ? acc.y : q2 ? acc.z : acc.w)
                  + (q0 ? gin4.x : q1 ? gin4.y : q2 ? gin4.z : gin4.w);
        float act = __builtin_fmaf(sig_fast(pre * fq), fq, bq);
        float v1 = __shfl_xor(act, 1);
        float v2 = __shfl_xor(act, 2);
        float v3 = __shfl_xor(act, 3);
        float ig = q0 ? act : q1 ? v1 : q2 ? v2 : v3;
        float fg = q0 ? v1  : q1 ? act: q2 ? v3 : v2;
        float gg = q0 ? v2  : q1 ? v3 : q2 ? act: v1;
        float og = q0 ? v3  : q1 ? v2 : q2 ? v1 : act;

        c = fg * c + ig * gg;
        float th = __builtin_fmaf(2.f, sig_fast(2.f * c), -1.f);
        h = og * th;

        if (q == 0) hb[p ^ 1][hslot] = h;
        if (out_x1 && q < 2) {
            int tg = dir ? (TT - 1 - (t_base + s)) : (t_base + s);
            size_t base = ((size_t)tg * BB + b) * 512;
            unsigned short hi, lo;
            split2(h, hi, lo);
            if (q == 0) out_x1[base + dir * HH + u] = hi;
            else        out_x1[base + 256 + dir * HH + u] = lo;
        }
        asm volatile("s_waitcnt lgkmcnt(0)" ::: "memory");
        __builtin_amdgcn_s_barrier();
        asm volatile("" ::: "memory");
        gin4 = gin4n;
    }
    if (q == 0) {
        h_state[sbase + u] = h;
        c_state[sbase + u] = c;
    }
}

// ---- FC head --------------------------------------------------------------
__global__ void fc_kernel(const float* __restrict__ h_state,  // (2,B,128)
                          const float* __restrict__ fc_w,     // (3,256)
                          const float* __restrict__ fc_b,     // (3,)
                          float* __restrict__ out) {          // (B,3)
    int tid = blockIdx.x * blockDim.x + threadIdx.x;
    if (tid >= BB * 3) return;
    int b = tid / 3;
    int c = tid % 3;
    float acc = 0.f;
    for (int j = 0; j < 256; ++j) {
        float v = (j < HH) ? h_state[((size_t)0 * BB + b) * HH + j]
                           : h_state[((size_t)1 * BB + b) * HH + (j - HH)];
        acc += v * fc_w[c * 256 + j];
    }
    out[b * 3 + c] = acc + fc_b[c];
}

extern "C" void kernel_launch(void* const* d_in, const int* in_sizes, int n_in,
                              void* d_out, int out_size, void* d_ws, size_t ws_size,
                              hipStream_t stream) {
    const int*   x        = (const int*)  d_in[0];
    const float* emb      = (const float*)d_in[1];
    const float* w_ih_l0  = (const float*)d_in[2];
    const float* w_hh_l0  = (const float*)d_in[3];
    const float* b_ih_l0  = (const float*)d_in[4];
    const float* b_hh_l0  = (const float*)d_in[5];
    const float* w_ih_l0r = (const float*)d_in[6];
    const float* w_hh_l0r = (const float*)d_in[7];
    const float* b_ih_l0r = (const float*)d_in[8];
    const float* b_hh_l0r = (const float*)d_in[9];
    const float* w_ih_l1  = (const float*)d_in[10];
    const float* w_hh_l1  = (const float*)d_in[11];
    const float* b_ih_l1  = (const float*)d_in[12];
    const float* b_hh_l1  = (const float*)d_in[13];
    const float* w_ih_l1r = (const float*)d_in[14];
    const float* w_hh_l1r = (const float*)d_in[15];
    const float* b_ih_l1r = (const float*)d_in[16];
    const float* b_hh_l1r = (const float*)d_in[17];
    const float* fc_w     = (const float*)d_in[18];
    const float* fc_b     = (const float*)d_in[19];
    float* out = (float*)d_out;
    (void)in_sizes; (void)n_in; (void)out_size;

    // ---- workspace layout ----
    size_t xs2_b   = (size_t)TT * BB * 256 * 2;         // 33.6 MB
    size_t x1_b    = (size_t)TT * BB * 512 * 2;         // 67.1 MB (bf16 hi|lo)
    size_t w2l0_b  = (size_t)512 * 256 * 2;             // 256 KB
    size_t w2l1_b  = (size_t)512 * 512 * 2;             // 512 KB
    size_t bias_b  = (size_t)1024 * 4;                  // 4 KB
    size_t wpk_b   = (size_t)128 * 128 * 4 * 4;         // 256 KB each
    size_t state_b = (size_t)2 * BB * HH * 4;           // 128 KB
    size_t fixed = xs2_b + x1_b + 2 * w2l0_b + 2 * w2l1_b + 2 * bias_b
                 + 4 * wpk_b + 2 * state_b + 4096;
    int TC = 512;
    while (TC > 8) {
        size_t chunk2 = (size_t)TC * BB * G4 * 4 * 2;
        if (fixed + chunk2 <= ws_size) break;
        TC >>= 1;
    }
    char* ws = (char*)d_ws;
    size_t off = 0;
    unsigned short* xs2   = (unsigned short*)(ws + off); off += xs2_b;
    unsigned short* x1_2  = (unsigned short*)(ws + off); off += x1_b;
    unsigned short* w2l0f = (unsigned short*)(ws + off); off += w2l0_b;   // cat: fwd..
    unsigned short* w2l0r = (unsigned short*)(ws + off); off += w2l0_b;   // ..bwd
    unsigned short* w2l1f = (unsigned short*)(ws + off); off += w2l1_b;
    unsigned short* w2l1r = (unsigned short*)(ws + off); off += w2l1_b;
    float* biasl0  = (float*)(ws + off); off += bias_b;
    float* biasl1  = (float*)(ws + off); off += bias_b;
    float* wpk0f   = (float*)(ws + off); off += wpk_b;
    float* wpk0r   = (float*)(ws + off); off += wpk_b;
    float* wpk1f   = (float*)(ws + off); off += wpk_b;
    float* wpk1r   = (float*)(ws + off); off += wpk_b;
    float* h_state = (float*)(ws + off); off += state_b;
    float* c_state = (float*)(ws + off); off += state_b;
    float* gxf     = (float*)(ws + off); off += (size_t)TC * BB * G4 * 4;
    float* gxr     = (float*)(ws + off);

    int NC = TT / TC;
    dim3 ggrid(8, TC);

    // ---- precompute packed/bf16 forms ----
    embed_cvt<<<TT * BB, 128, 0, stream>>>(x, emb, xs2);
    wcvt<<<512, 128, 0, stream>>>(w_ih_l0,  EE, 128, w2l0f);
    wcvt<<<512, 128, 0, stream>>>(w_ih_l0r, EE, 128, w2l0r);
    wcvt<<<512, 256, 0, stream>>>(w_ih_l1,  K1, 256, w2l1f);
    wcvt<<<512, 256, 0, stream>>>(w_ih_l1r, K1, 256, w2l1r);
    bias_cat<<<4, 256, 0, stream>>>(b_ih_l0, b_hh_l0, b_ih_l0r, b_hh_l0r, biasl0);
    bias_cat<<<4, 256, 0, stream>>>(b_ih_l1, b_hh_l1, b_ih_l1r, b_hh_l1r, biasl1);
    whh_pack<<<128, 128, 0, stream>>>(w_hh_l0,  wpk0f);
    whh_pack<<<128, 128, 0, stream>>>(w_hh_l0r, wpk0r);
    whh_pack<<<128, 128, 0, stream>>>(w_hh_l1,  wpk1f);
    whh_pack<<<128, 128, 0, stream>>>(w_hh_l1r, wpk1r);

    // ---- layer 0 ----
    hipMemsetAsync(h_state, 0, state_b, stream);
    hipMemsetAsync(c_state, 0, state_b, stream);
    for (int ci = 0; ci < NC; ++ci) {
        int t0 = ci * TC;
        gemm_mfma<256><<<ggrid, 256, 0, stream>>>(xs2, w2l0f, biasl0, gxf, gxr, t0);
        lstm_chunk<<<256, 512, 0, stream>>>(gxf, gxr, wpk0f, wpk0r,
                                            h_state, c_state, x1_2, t0, TC);
    }
    // ---- layer 1 ----
    hipMemsetAsync(h_state, 0, state_b, stream);
    hipMemsetAsync(c_state, 0, state_b, stream);
    for (int ci = 0; ci < NC; ++ci) {
        int t0 = ci * TC;
        gemm_mfma<512><<<ggrid, 256, 0, stream>>>(x1_2, w2l1f, biasl1, gxf, gxr, t0);
        lstm_chunk<<<256, 512, 0, stream>>>(gxf, gxr, wpk1f, wpk1r,
                                            h_state, c_state, nullptr, t0, TC);
    }
    // ---- FC head ----
    fc_kernel<<<2, 192, 0, stream>>>(h_state, fc_w, fc_b, out);
}

// Round 7
// 971.773 us; speedup vs baseline: 1.1694x; 1.1694x over previous
//
#include <hip/hip_runtime.h>
#include <hip/hip_bf16.h>
#include <math.h>

#define TT 512   // T
#define BB 128   // B
#define EE 100   // embed dim
#define HH 128   // hidden
#define G4 512   // 4*H
#define K1 256   // 2*H

typedef __attribute__((ext_vector_type(8))) short bf16x8;
typedef __attribute__((ext_vector_type(4))) float f32x4;

__device__ inline void split2(float v, unsigned short& hi, unsigned short& lo) {
    __hip_bfloat16 h = __float2bfloat16(v);
    float hf = __bfloat162float(h);
    __hip_bfloat16 l = __float2bfloat16(v - hf);
    hi = *reinterpret_cast<unsigned short*>(&h);
    lo = *reinterpret_cast<unsigned short*>(&l);
}

__device__ inline void gload16(const void* g, void* l) {
    __builtin_amdgcn_global_load_lds(
        (const __attribute__((address_space(1))) void*)g,
        (__attribute__((address_space(3))) void*)l, 16, 0, 0);
}

// quad-scope DPP move (pure VALU, no LDS pipe)
template<int CTRL>
__device__ inline float dppf(float x) {
    int r = __builtin_amdgcn_update_dpp(0, __float_as_int(x), CTRL, 0xF, 0xF, true);
    return __int_as_float(r);
}
// quad_perm ctrls: xor1=0xB1, xor2=0x4E, bcast0=0x00, bcast1=0x55, bcast2=0xAA, bcast3=0xFF

// ---- embedding -> xs2 bf16 [hi(128) | lo(128)] per (t,b) row ---------------
__global__ void embed_cvt(const int* __restrict__ x, const float* __restrict__ emb,
                          unsigned short* __restrict__ xs2) {
    int row = blockIdx.x;          // t*B + b
    int k = threadIdx.x;           // 0..127
    int b = row & 127, t = row >> 7;
    int tok = x[b * TT + t];
    float v = (k < EE) ? emb[(size_t)tok * EE + k] : 0.f;
    unsigned short hi, lo;
    split2(v, hi, lo);
    xs2[(size_t)row * 256 + k] = hi;
    xs2[(size_t)row * 256 + 128 + k] = lo;
}

// ---- weight -> bf16 [hi(Kp)|lo(Kp)], rows permuted to unit-major, gate
// order [i,g,f,o]: dst col n' = unit n'>>2, slot j=n'&3, gate=((j&1)<<1)|(j>>1)
__global__ void wcvt(const float* __restrict__ src, int Kin, int Kp,
                     unsigned short* __restrict__ dst) {
    int n = blockIdx.x;            // 0..511 (dst row)
    int k = threadIdx.x;           // 0..Kp-1
    int j = n & 3;
    int gate = ((j & 1) << 1) | (j >> 1);
    int r = gate * 128 + (n >> 2);
    float v = (k < Kin) ? src[(size_t)r * Kin + k] : 0.f;
    unsigned short hi, lo;
    split2(v, hi, lo);
    dst[(size_t)n * 2 * Kp + k] = hi;
    dst[(size_t)n * 2 * Kp + Kp + k] = lo;
}

// ---- bias: dst[dir*512+n] = bih[perm(n)] + bhh[perm(n)], same perm --------
__global__ void bias_cat(const float* __restrict__ bihf, const float* __restrict__ bhhf,
                         const float* __restrict__ bihr, const float* __restrict__ bhhr,
                         float* __restrict__ dst) {
    int n = blockIdx.x * 256 + threadIdx.x;   // 0..1023
    int d = n >> 9, m = n & 511;
    int j = m & 3;
    int gate = ((j & 1) << 1) | (j >> 1);
    int src = gate * 128 + (m >> 2);
    const float* a = d ? bihr : bihf;
    const float* c = d ? bhhr : bhhf;
    dst[n] = a[src] + c[src];
}

// ---- pack whh -> wpk[u][k][gate i,f,g,o] (float4 per (u,k)) ---------------
__global__ void whh_pack(const float* __restrict__ whh, float* __restrict__ dst) {
    int u = blockIdx.x;            // 0..127
    int k = threadIdx.x;           // 0..127
    float4 v;
    v.x = whh[((size_t)(0 * 128 + u)) * 128 + k];
    v.y = whh[((size_t)(1 * 128 + u)) * 128 + k];
    v.z = whh[((size_t)(2 * 128 + u)) * 128 + k];
    v.w = whh[((size_t)(3 * 128 + u)) * 128 + k];
    reinterpret_cast<float4*>(dst)[(size_t)u * 128 + k] = v;
}

// ---- merged MFMA GEMM (fwd+bwd): grid (8, TC) -----------------------------
template<int K2>
__global__ __launch_bounds__(256) void gemm_mfma(
    const unsigned short* __restrict__ A2,
    const unsigned short* __restrict__ W2cat,
    const float* __restrict__ biascat,     // (1024,) permuted, bih+bhh
    float* __restrict__ Cf, float* __restrict__ Cr,
    int t_base)
{
    __shared__ bf16x8 As[1024];   // 128 rows x 128 B (64 bf16), swizzled
    __shared__ bf16x8 Bs[1024];
    int tid = threadIdx.x;
    int s = blockIdx.y;
    int dir = blockIdx.x >> 2;
    int nBase = (blockIdx.x & 3) * 128;
    int t = dir ? (TT - 1 - t_base - s) : (t_base + s);
    float* C = dir ? Cr : Cf;
    const unsigned short* Abase = A2 + (size_t)t * BB * K2;
    const unsigned short* Wbase = W2cat + (size_t)(dir * 512 + nBase) * K2;
    int lane = tid & 63, wid = tid >> 6;
    int wr = wid >> 1, wc = wid & 1;
    int l15 = lane & 15, g = lane >> 4;

    f32x4 acc[4][4];
    const f32x4 z = {0.f, 0.f, 0.f, 0.f};
    #pragma unroll
    for (int i = 0; i < 4; ++i)
        #pragma unroll
        for (int j = 0; j < 4; ++j) acc[i][j] = z;

    for (int kt = 0; kt < K2 / 64; ++kt) {
        #pragma unroll
        for (int j = 0; j < 4; ++j) {
            int p = tid + j * 256;
            int row = p >> 3;
            int k16 = (p & 7) ^ (row & 7);   // pre-swizzled source chunk
            size_t goff = (size_t)row * K2 + kt * 64 + k16 * 8;
            gload16(Abase + goff, &As[p]);
            gload16(Wbase + goff, &Bs[p]);
        }
        __syncthreads();
        #pragma unroll
        for (int ks = 0; ks < 2; ++ks) {
            bf16x8 af[4], bfr[4];
            #pragma unroll
            for (int i = 0; i < 4; ++i) {
                int arow = wr * 64 + i * 16 + l15;
                int abyte = arow * 128 + ((ks * 64 + g * 16) ^ ((arow & 7) << 4));
                af[i] = As[abyte >> 4];
                int brow = wc * 64 + i * 16 + l15;
                int bbyte = brow * 128 + ((ks * 64 + g * 16) ^ ((brow & 7) << 4));
                bfr[i] = Bs[bbyte >> 4];
            }
            #pragma unroll
            for (int i = 0; i < 4; ++i)
                #pragma unroll
                for (int j = 0; j < 4; ++j)
                    acc[i][j] = __builtin_amdgcn_mfma_f32_16x16x32_bf16(
                        af[i], bfr[j], acc[i][j], 0, 0, 0);
        }
        __syncthreads();
    }
    #pragma unroll
    for (int i = 0; i < 4; ++i) {
        size_t crow0 = (size_t)s * 128 + wr * 64 + i * 16 + g * 4;
        #pragma unroll
        for (int j = 0; j < 4; ++j) {
            int col = nBase + wc * 64 + j * 16 + l15;
            float bsum = biascat[dir * 512 + col];
            #pragma unroll
            for (int r = 0; r < 4; ++r)
                C[(crow0 + r) * G4 + col] = acc[i][j][r] + bsum;
        }
    }
}

__device__ inline float sig_fast(float z) {
    return __builtin_amdgcn_rcpf(1.f + __expf(-z));
}

// ---- LSTM recurrence: one block per (dir, b); 512 thr; quad-per-unit ------
// thread (u = tid>>2, q = tid&3): K-slice [32q,32q+32) of all 4 gate rows of
// unit u. ALL cross-lane traffic via quad DPP (VALU), zero LDS-pipe shuffles.
// Reduce-scatter: lane q ends owning gate [i,g,f,o][q]; scalar gin per lane.
__global__ __launch_bounds__(512, 2) void lstm_chunk(
    const float* __restrict__ gxf,        // (TC*B, 512) unit-major [i,g,f,o]
    const float* __restrict__ gxr,
    const float* __restrict__ wpkf,       // (128,128,4) packed whh fwd (i,f,g,o)
    const float* __restrict__ wpkr,
    float* __restrict__ h_state,          // (2, B, 128)
    float* __restrict__ c_state,          // (2, B, 128)
    unsigned short* __restrict__ out_x1,  // x1_2 (T*B,512) bf16 [hi|lo], or null
    int t_base, int TC)
{
    int blk = blockIdx.x;
    int dir = blk >> 7;
    int b   = blk & 127;
    const float* gx  = dir ? gxr : gxf;
    const float* wpk = dir ? wpkr : wpkf;
    int tid = threadIdx.x;
    int u = tid >> 2, q = tid & 3;

    // 32 named f32x4 weight registers: w_i = gates(i,f,g,o) at k = q*32+i
    const f32x4* wp4 = reinterpret_cast<const f32x4*>(wpk) + ((size_t)u * 128 + q * 32);
#define LW(i) const f32x4 w##i = wp4[i];
    LW(0)  LW(1)  LW(2)  LW(3)  LW(4)  LW(5)  LW(6)  LW(7)
    LW(8)  LW(9)  LW(10) LW(11) LW(12) LW(13) LW(14) LW(15)
    LW(16) LW(17) LW(18) LW(19) LW(20) LW(21) LW(22) LW(23)
    LW(24) LW(25) LW(26) LW(27) LW(28) LW(29) LW(30) LW(31)
#undef LW

    // ping-pong h buffer: quarter q at float offset 40q (bank-shifted, 16B-aligned)
    __shared__ float hb[2][160];
    int sbase = (dir * BB + b) * HH;
    int hslot = (u >> 5) * 40 + (u & 31);
    float c = c_state[sbase + u];
    float h = 0.f;
    if (q == 0) hb[0][hslot] = h_state[sbase + u];
    __syncthreads();

    const float* gxrow = gx + b * G4 + tid;     // scalar gin: element (u, slot q)
    float gin = gxrow[0];
    bool odd2 = (q & 2) != 0;
    float fq = (q == 1) ? 2.f : 1.f;            // lane-gate map [i,g,f,o]
    float bq = (q == 1) ? -1.f : 0.f;

    for (int s = 0; s < TC; ++s) {
        int p = s & 1;
        int sn = (s + 1 < TC) ? s + 1 : s;
        float gin_next = gxrow[(size_t)sn * BB * G4];

        const float4* hb4 = reinterpret_cast<const float4*>(&hb[p][40 * q]);
        float4 hv0 = hb4[0], hv1 = hb4[1], hv2 = hb4[2], hv3 = hb4[3];
        float4 hv4 = hb4[4], hv5 = hb4[5], hv6 = hb4[6], hv7 = hb4[7];

        f32x4 a0 = {0.f,0.f,0.f,0.f}, a1 = {0.f,0.f,0.f,0.f};
        f32x4 a2 = {0.f,0.f,0.f,0.f}, a3 = {0.f,0.f,0.f,0.f};
#define FM(i0,i1,i2,i3,HV) { \
        f32x4 hh; \
        hh = f32x4{HV.x,HV.x,HV.x,HV.x}; a0 = __builtin_elementwise_fma(w##i0, hh, a0); \
        hh = f32x4{HV.y,HV.y,HV.y,HV.y}; a1 = __builtin_elementwise_fma(w##i1, hh, a1); \
        hh = f32x4{HV.z,HV.z,HV.z,HV.z}; a2 = __builtin_elementwise_fma(w##i2, hh, a2); \
        hh = f32x4{HV.w,HV.w,HV.w,HV.w}; a3 = __builtin_elementwise_fma(w##i3, hh, a3); }
        FM(0,1,2,3,hv0)    FM(4,5,6,7,hv1)    FM(8,9,10,11,hv2)  FM(12,13,14,15,hv3)
        FM(16,17,18,19,hv4) FM(20,21,22,23,hv5) FM(24,25,26,27,hv6) FM(28,29,30,31,hv7)
#undef FM
        f32x4 acc = (a0 + a1) + (a2 + a3);      // (i,f,g,o) partial over slice q

        // reduce-scatter via quad DPP: stage 1 (xor 1)
        float xs = acc.x + dppf<0xB1>(acc.x);   // i over {q,q^1}
        float ys = acc.y + dppf<0xB1>(acc.y);   // f
        float zs = acc.z + dppf<0xB1>(acc.z);   // g
        float ws = acc.w + dppf<0xB1>(acc.w);   // o
        bool oddq = (q & 1) != 0;
        float sa = oddq ? zs : xs;              // even: i-partial, odd: g-partial
        float sb = oddq ? ws : ys;              // even: f-partial, odd: o-partial
        // stage 2 (xor 2)
        float sa2 = sa + dppf<0x4E>(sa);        // lanes 0,2: full i | lanes 1,3: full g
        float sb2 = sb + dppf<0x4E>(sb);        // lanes 0,2: full f | lanes 1,3: full o
        float pre_dot = odd2 ? sb2 : sa2;       // lane q owns gate [i,g,f,o][q]

        float pre = pre_dot + gin;
        float act = __builtin_fmaf(sig_fast(pre * fq), fq, bq);

        // quad broadcast of the 4 activations (lane-gate map [i,g,f,o])
        float ig = dppf<0x00>(act);
        float gg = dppf<0x55>(act);
        float fg = dppf<0xAA>(act);
        float og = dppf<0xFF>(act);

        c = fg * c + ig * gg;
        float th = __builtin_fmaf(2.f, sig_fast(2.f * c), -1.f);
        h = og * th;

        if (q == 0) hb[p ^ 1][hslot] = h;
        if (out_x1 && q < 2) {
            int tg = dir ? (TT - 1 - (t_base + s)) : (t_base + s);
            size_t base = ((size_t)tg * BB + b) * 512;
            unsigned short hi, lo;
            split2(h, hi, lo);
            if (q == 0) out_x1[base + dir * HH + u] = hi;
            else        out_x1[base + 256 + dir * HH + u] = lo;
        }
        asm volatile("s_waitcnt lgkmcnt(0)" ::: "memory");
        __builtin_amdgcn_s_barrier();
        asm volatile("" ::: "memory");
        gin = gin_next;
        gxrow += (size_t)0;                      // keep pointer loop-invariant
    }
    if (q == 0) {
        h_state[sbase + u] = h;
        c_state[sbase + u] = c;
    }
}

// ---- FC head --------------------------------------------------------------
__global__ void fc_kernel(const float* __restrict__ h_state,  // (2,B,128)
                          const float* __restrict__ fc_w,     // (3,256)
                          const float* __restrict__ fc_b,     // (3,)
                          float* __restrict__ out) {          // (B,3)
    int tid = blockIdx.x * blockDim.x + threadIdx.x;
    if (tid >= BB * 3) return;
    int b = tid / 3;
    int c = tid % 3;
    float acc = 0.f;
    for (int j = 0; j < 256; ++j) {
        float v = (j < HH) ? h_state[((size_t)0 * BB + b) * HH + j]
                           : h_state[((size_t)1 * BB + b) * HH + (j - HH)];
        acc += v * fc_w[c * 256 + j];
    }
    out[b * 3 + c] = acc + fc_b[c];
}

extern "C" void kernel_launch(void* const* d_in, const int* in_sizes, int n_in,
                              void* d_out, int out_size, void* d_ws, size_t ws_size,
                              hipStream_t stream) {
    const int*   x        = (const int*)  d_in[0];
    const float* emb      = (const float*)d_in[1];
    const float* w_ih_l0  = (const float*)d_in[2];
    const float* w_hh_l0  = (const float*)d_in[3];
    const float* b_ih_l0  = (const float*)d_in[4];
    const float* b_hh_l0  = (const float*)d_in[5];
    const float* w_ih_l0r = (const float*)d_in[6];
    const float* w_hh_l0r = (const float*)d_in[7];
    const float* b_ih_l0r = (const float*)d_in[8];
    const float* b_hh_l0r = (const float*)d_in[9];
    const float* w_ih_l1  = (const float*)d_in[10];
    const float* w_hh_l1  = (const float*)d_in[11];
    const float* b_ih_l1  = (const float*)d_in[12];
    const float* b_hh_l1  = (const float*)d_in[13];
    const float* w_ih_l1r = (const float*)d_in[14];
    const float* w_hh_l1r = (const float*)d_in[15];
    const float* b_ih_l1r = (const float*)d_in[16];
    const float* b_hh_l1r = (const float*)d_in[17];
    const float* fc_w     = (const float*)d_in[18];
    const float* fc_b     = (const float*)d_in[19];
    float* out = (float*)d_out;
    (void)in_sizes; (void)n_in; (void)out_size;

    // ---- workspace layout ----
    size_t xs2_b   = (size_t)TT * BB * 256 * 2;         // 33.6 MB
    size_t x1_b    = (size_t)TT * BB * 512 * 2;         // 67.1 MB (bf16 hi|lo)
    size_t w2l0_b  = (size_t)512 * 256 * 2;             // 256 KB
    size_t w2l1_b  = (size_t)512 * 512 * 2;             // 512 KB
    size_t bias_b  = (size_t)1024 * 4;                  // 4 KB
    size_t wpk_b   = (size_t)128 * 128 * 4 * 4;         // 256 KB each
    size_t state_b = (size_t)2 * BB * HH * 4;           // 128 KB
    size_t fixed = xs2_b + x1_b + 2 * w2l0_b + 2 * w2l1_b + 2 * bias_b
                 + 4 * wpk_b + 2 * state_b + 4096;
    int TC = 512;
    while (TC > 8) {
        size_t chunk2 = (size_t)TC * BB * G4 * 4 * 2;
        if (fixed + chunk2 <= ws_size) break;
        TC >>= 1;
    }
    char* ws = (char*)d_ws;
    size_t off = 0;
    unsigned short* xs2   = (unsigned short*)(ws + off); off += xs2_b;
    unsigned short* x1_2  = (unsigned short*)(ws + off); off += x1_b;
    unsigned short* w2l0f = (unsigned short*)(ws + off); off += w2l0_b;   // cat: fwd..
    unsigned short* w2l0r = (unsigned short*)(ws + off); off += w2l0_b;   // ..bwd
    unsigned short* w2l1f = (unsigned short*)(ws + off); off += w2l1_b;
    unsigned short* w2l1r = (unsigned short*)(ws + off); off += w2l1_b;
    float* biasl0  = (float*)(ws + off); off += bias_b;
    float* biasl1  = (float*)(ws + off); off += bias_b;
    float* wpk0f   = (float*)(ws + off); off += wpk_b;
    float* wpk0r   = (float*)(ws + off); off += wpk_b;
    float* wpk1f   = (float*)(ws + off); off += wpk_b;
    float* wpk1r   = (float*)(ws + off); off += wpk_b;
    float* h_state = (float*)(ws + off); off += state_b;
    float* c_state = (float*)(ws + off); off += state_b;
    float* gxf     = (float*)(ws + off); off += (size_t)TC * BB * G4 * 4;
    float* gxr     = (float*)(ws + off);

    int NC = TT / TC;
    dim3 ggrid(8, TC);

    // ---- precompute packed/bf16 forms ----
    embed_cvt<<<TT * BB, 128, 0, stream>>>(x, emb, xs2);
    wcvt<<<512, 128, 0, stream>>>(w_ih_l0,  EE, 128, w2l0f);
    wcvt<<<512, 128, 0, stream>>>(w_ih_l0r, EE, 128, w2l0r);
    wcvt<<<512, 256, 0, stream>>>(w_ih_l1,  K1, 256, w2l1f);
    wcvt<<<512, 256, 0, stream>>>(w_ih_l1r, K1, 256, w2l1r);
    bias_cat<<<4, 256, 0, stream>>>(b_ih_l0, b_hh_l0, b_ih_l0r, b_hh_l0r, biasl0);
    bias_cat<<<4, 256, 0, stream>>>(b_ih_l1, b_hh_l1, b_ih_l1r, b_hh_l1r, biasl1);
    whh_pack<<<128, 128, 0, stream>>>(w_hh_l0,  wpk0f);
    whh_pack<<<128, 128, 0, stream>>>(w_hh_l0r, wpk0r);
    whh_pack<<<128, 128, 0, stream>>>(w_hh_l1,  wpk1f);
    whh_pack<<<128, 128, 0, stream>>>(w_hh_l1r, wpk1r);

    // ---- layer 0 ----
    hipMemsetAsync(h_state, 0, state_b, stream);
    hipMemsetAsync(c_state, 0, state_b, stream);
    for (int ci = 0; ci < NC; ++ci) {
        int t0 = ci * TC;
        gemm_mfma<256><<<ggrid, 256, 0, stream>>>(xs2, w2l0f, biasl0, gxf, gxr, t0);
        lstm_chunk<<<256, 512, 0, stream>>>(gxf, gxr, wpk0f, wpk0r,
                                            h_state, c_state, x1_2, t0, TC);
    }
    // ---- layer 1 ----
    hipMemsetAsync(h_state, 0, state_b, stream);
    hipMemsetAsync(c_state, 0, state_b, stream);
    for (int ci = 0; ci < NC; ++ci) {
        int t0 = ci * TC;
        gemm_mfma<512><<<ggrid, 256, 0, stream>>>(x1_2, w2l1f, biasl1, gxf, gxr, t0);
        lstm_chunk<<<256, 512, 0, stream>>>(gxf, gxr, wpk1f, wpk1r,
                                            h_state, c_state, nullptr, t0, TC);
    }
    // ---- FC head ----
    fc_kernel<<<2, 192, 0, stream>>>(h_state, fc_w, fc_b, out);
}

// Round 8
// 872.890 us; speedup vs baseline: 1.3019x; 1.1133x over previous
//
#include <hip/hip_runtime.h>
#include <hip/hip_bf16.h>
#include <math.h>

#define TT 512   // T
#define BB 128   // B
#define EE 100   // embed dim
#define HH 128   // hidden
#define G4 512   // 4*H
#define K1 256   // 2*H

typedef __attribute__((ext_vector_type(8))) short bf16x8;
typedef __attribute__((ext_vector_type(4))) float f32x4;

__device__ inline unsigned short bf16_rne(float v) {
    __hip_bfloat16 h = __float2bfloat16(v);
    return *reinterpret_cast<unsigned short*>(&h);
}

__device__ inline void gload16(const void* g, void* l) {
    __builtin_amdgcn_global_load_lds(
        (const __attribute__((address_space(1))) void*)g,
        (__attribute__((address_space(3))) void*)l, 16, 0, 0);
}

// quad-scope DPP move (pure VALU, no LDS pipe)
template<int CTRL>
__device__ inline float dppf(float x) {
    int r = __builtin_amdgcn_update_dpp(0, __float_as_int(x), CTRL, 0xF, 0xF, true);
    return __int_as_float(r);
}
// quad_perm ctrls: xor1=0xB1, xor2=0x4E, bcast0=0x00, bcast1=0x55, bcast2=0xAA, bcast3=0xFF

// ---- embedding -> xs2 bf16 hi, row = 128 shorts ---------------------------
__global__ void embed_cvt(const int* __restrict__ x, const float* __restrict__ emb,
                          unsigned short* __restrict__ xs2) {
    int row = blockIdx.x;          // t*B + b
    int k = threadIdx.x;           // 0..127
    int b = row & 127, t = row >> 7;
    int tok = x[b * TT + t];
    float v = (k < EE) ? emb[(size_t)tok * EE + k] : 0.f;
    xs2[(size_t)row * 128 + k] = bf16_rne(v);
}

// ---- weight -> bf16 hi, rows permuted to unit-major, gate order [i,g,f,o] --
__global__ void wcvt(const float* __restrict__ src, int Kin, int Kp,
                     unsigned short* __restrict__ dst) {
    int n = blockIdx.x;            // 0..511 (dst row)
    int k = threadIdx.x;           // 0..Kp-1
    int j = n & 3;
    int gate = ((j & 1) << 1) | (j >> 1);
    int r = gate * 128 + (n >> 2);
    float v = (k < Kin) ? src[(size_t)r * Kin + k] : 0.f;
    dst[(size_t)n * Kp + k] = bf16_rne(v);
}

// ---- bias: dst[dir*512+n] = bih[perm(n)] + bhh[perm(n)], same perm --------
__global__ void bias_cat(const float* __restrict__ bihf, const float* __restrict__ bhhf,
                         const float* __restrict__ bihr, const float* __restrict__ bhhr,
                         float* __restrict__ dst) {
    int n = blockIdx.x * 256 + threadIdx.x;   // 0..1023
    int d = n >> 9, m = n & 511;
    int j = m & 3;
    int gate = ((j & 1) << 1) | (j >> 1);
    int src = gate * 128 + (m >> 2);
    const float* a = d ? bihr : bihf;
    const float* c = d ? bhhr : bhhf;
    dst[n] = a[src] + c[src];
}

// ---- pack whh -> wpk[u][k][gate i,f,g,o] (float4 per (u,k)) ---------------
__global__ void whh_pack(const float* __restrict__ whh, float* __restrict__ dst) {
    int u = blockIdx.x;            // 0..127
    int k = threadIdx.x;           // 0..127
    float4 v;
    v.x = whh[((size_t)(0 * 128 + u)) * 128 + k];
    v.y = whh[((size_t)(1 * 128 + u)) * 128 + k];
    v.z = whh[((size_t)(2 * 128 + u)) * 128 + k];
    v.w = whh[((size_t)(3 * 128 + u)) * 128 + k];
    reinterpret_cast<float4*>(dst)[(size_t)u * 128 + k] = v;
}

// ---- merged MFMA GEMM (fwd+bwd): grid (8, TC) -----------------------------
template<int K2>
__global__ __launch_bounds__(256) void gemm_mfma(
    const unsigned short* __restrict__ A2,
    const unsigned short* __restrict__ W2cat,
    const float* __restrict__ biascat,     // (1024,) permuted, bih+bhh
    float* __restrict__ Cf, float* __restrict__ Cr,
    int t_base)
{
    __shared__ bf16x8 As[1024];   // 128 rows x 128 B (64 bf16), swizzled
    __shared__ bf16x8 Bs[1024];
    int tid = threadIdx.x;
    int s = blockIdx.y;
    int dir = blockIdx.x >> 2;
    int nBase = (blockIdx.x & 3) * 128;
    int t = dir ? (TT - 1 - t_base - s) : (t_base + s);
    float* C = dir ? Cr : Cf;
    const unsigned short* Abase = A2 + (size_t)t * BB * K2;
    const unsigned short* Wbase = W2cat + (size_t)(dir * 512 + nBase) * K2;
    int lane = tid & 63, wid = tid >> 6;
    int wr = wid >> 1, wc = wid & 1;
    int l15 = lane & 15, g = lane >> 4;

    f32x4 acc[4][4];
    const f32x4 z = {0.f, 0.f, 0.f, 0.f};
    #pragma unroll
    for (int i = 0; i < 4; ++i)
        #pragma unroll
        for (int j = 0; j < 4; ++j) acc[i][j] = z;

    for (int kt = 0; kt < K2 / 64; ++kt) {
        #pragma unroll
        for (int j = 0; j < 4; ++j) {
            int p = tid + j * 256;
            int row = p >> 3;
            int k16 = (p & 7) ^ (row & 7);   // pre-swizzled source chunk
            size_t goff = (size_t)row * K2 + kt * 64 + k16 * 8;
            gload16(Abase + goff, &As[p]);
            gload16(Wbase + goff, &Bs[p]);
        }
        __syncthreads();
        #pragma unroll
        for (int ks = 0; ks < 2; ++ks) {
            bf16x8 af[4], bfr[4];
            #pragma unroll
            for (int i = 0; i < 4; ++i) {
                int arow = wr * 64 + i * 16 + l15;
                int abyte = arow * 128 + ((ks * 64 + g * 16) ^ ((arow & 7) << 4));
                af[i] = As[abyte >> 4];
                int brow = wc * 64 + i * 16 + l15;
                int bbyte = brow * 128 + ((ks * 64 + g * 16) ^ ((brow & 7) << 4));
                bfr[i] = Bs[bbyte >> 4];
            }
            #pragma unroll
            for (int i = 0; i < 4; ++i)
                #pragma unroll
                for (int j = 0; j < 4; ++j)
                    acc[i][j] = __builtin_amdgcn_mfma_f32_16x16x32_bf16(
                        af[i], bfr[j], acc[i][j], 0, 0, 0);
        }
        __syncthreads();
    }
    #pragma unroll
    for (int i = 0; i < 4; ++i) {
        size_t crow0 = (size_t)s * 128 + wr * 64 + i * 16 + g * 4;
        #pragma unroll
        for (int j = 0; j < 4; ++j) {
            int col = nBase + wc * 64 + j * 16 + l15;
            float bsum = biascat[dir * 512 + col];
            #pragma unroll
            for (int r = 0; r < 4; ++r)
                C[(crow0 + r) * G4 + col] = acc[i][j][r] + bsum;
        }
    }
}

__device__ inline float sig_fast(float z) {
    return __builtin_amdgcn_rcpf(1.f + __expf(-z));
}

// ---- LSTM recurrence: one block per (dir, b); 512 thr; quad-per-unit ------
// thread (u = tid>>2, q = tid&3): K-slice [32q,32q+32) of all 4 gate rows of
// unit u. ALL cross-lane traffic via quad DPP (VALU), zero LDS-pipe shuffles.
__global__ __launch_bounds__(512, 2) void lstm_chunk(
    const float* __restrict__ gxf,        // (TC*B, 512) unit-major [i,g,f,o]
    const float* __restrict__ gxr,
    const float* __restrict__ wpkf,       // (128,128,4) packed whh fwd (i,f,g,o)
    const float* __restrict__ wpkr,
    float* __restrict__ h_state,          // (2, B, 128)
    float* __restrict__ c_state,          // (2, B, 128)
    unsigned short* __restrict__ out_x1,  // x1 (T*B,256) bf16 hi, or null
    int t_base, int TC)
{
    int blk = blockIdx.x;
    int dir = blk >> 7;
    int b   = blk & 127;
    const float* gx  = dir ? gxr : gxf;
    const float* wpk = dir ? wpkr : wpkf;
    int tid = threadIdx.x;
    int u = tid >> 2, q = tid & 3;

    // 32 named f32x4 weight registers: w_i = gates(i,f,g,o) at k = q*32+i
    const f32x4* wp4 = reinterpret_cast<const f32x4*>(wpk) + ((size_t)u * 128 + q * 32);
#define LW(i) const f32x4 w##i = wp4[i];
    LW(0)  LW(1)  LW(2)  LW(3)  LW(4)  LW(5)  LW(6)  LW(7)
    LW(8)  LW(9)  LW(10) LW(11) LW(12) LW(13) LW(14) LW(15)
    LW(16) LW(17) LW(18) LW(19) LW(20) LW(21) LW(22) LW(23)
    LW(24) LW(25) LW(26) LW(27) LW(28) LW(29) LW(30) LW(31)
#undef LW

    // ping-pong h buffer: quarter q at float offset 40q (bank-shifted, 16B-aligned)
    __shared__ float hb[2][160];
    int sbase = (dir * BB + b) * HH;
    int hslot = (u >> 5) * 40 + (u & 31);
    float c = c_state[sbase + u];
    float h = 0.f;
    if (q == 0) hb[0][hslot] = h_state[sbase + u];
    __syncthreads();

    const float* gxrow = gx + b * G4 + tid;     // scalar gin: element (u, slot q)
    float gin = gxrow[0];
    bool odd2 = (q & 2) != 0;
    float fq = (q == 1) ? 2.f : 1.f;            // lane-gate map [i,g,f,o]
    float bq = (q == 1) ? -1.f : 0.f;

    for (int s = 0; s < TC; ++s) {
        int p = s & 1;
        int sn = (s + 1 < TC) ? s + 1 : s;
        float gin_next = gxrow[(size_t)sn * BB * G4];

        const float4* hb4 = reinterpret_cast<const float4*>(&hb[p][40 * q]);
        float4 hv0 = hb4[0], hv1 = hb4[1], hv2 = hb4[2], hv3 = hb4[3];
        float4 hv4 = hb4[4], hv5 = hb4[5], hv6 = hb4[6], hv7 = hb4[7];

        f32x4 a0 = {0.f,0.f,0.f,0.f}, a1 = {0.f,0.f,0.f,0.f};
        f32x4 a2 = {0.f,0.f,0.f,0.f}, a3 = {0.f,0.f,0.f,0.f};
#define FM(i0,i1,i2,i3,HV) { \
        f32x4 hh; \
        hh = f32x4{HV.x,HV.x,HV.x,HV.x}; a0 = __builtin_elementwise_fma(w##i0, hh, a0); \
        hh = f32x4{HV.y,HV.y,HV.y,HV.y}; a1 = __builtin_elementwise_fma(w##i1, hh, a1); \
        hh = f32x4{HV.z,HV.z,HV.z,HV.z}; a2 = __builtin_elementwise_fma(w##i2, hh, a2); \
        hh = f32x4{HV.w,HV.w,HV.w,HV.w}; a3 = __builtin_elementwise_fma(w##i3, hh, a3); }
        FM(0,1,2,3,hv0)    FM(4,5,6,7,hv1)    FM(8,9,10,11,hv2)  FM(12,13,14,15,hv3)
        FM(16,17,18,19,hv4) FM(20,21,22,23,hv5) FM(24,25,26,27,hv6) FM(28,29,30,31,hv7)
#undef FM
        f32x4 acc = (a0 + a1) + (a2 + a3);      // (i,f,g,o) partial over slice q

        // reduce-scatter via quad DPP: stage 1 (xor 1)
        float xs = acc.x + dppf<0xB1>(acc.x);   // i over {q,q^1}
        float ys = acc.y + dppf<0xB1>(acc.y);   // f
        float zs = acc.z + dppf<0xB1>(acc.z);   // g
        float ws = acc.w + dppf<0xB1>(acc.w);   // o
        bool oddq = (q & 1) != 0;
        float sa = oddq ? zs : xs;              // even: i-partial, odd: g-partial
        float sb = oddq ? ws : ys;              // even: f-partial, odd: o-partial
        // stage 2 (xor 2)
        float sa2 = sa + dppf<0x4E>(sa);        // lanes 0,2: full i | lanes 1,3: full g
        float sb2 = sb + dppf<0x4E>(sb);        // lanes 0,2: full f | lanes 1,3: full o
        float pre_dot = odd2 ? sb2 : sa2;       // lane q owns gate [i,g,f,o][q]

        float pre = pre_dot + gin;
        float act = __builtin_fmaf(sig_fast(pre * fq), fq, bq);

        // quad broadcast of the 4 activations (lane-gate map [i,g,f,o])
        float ig = dppf<0x00>(act);
        float gg = dppf<0x55>(act);
        float fg = dppf<0xAA>(act);
        float og = dppf<0xFF>(act);

        c = fg * c + ig * gg;
        float th = __builtin_fmaf(2.f, sig_fast(2.f * c), -1.f);
        h = og * th;

        if (q == 0) {
            hb[p ^ 1][hslot] = h;
            if (out_x1) {
                int tg = dir ? (TT - 1 - (t_base + s)) : (t_base + s);
                out_x1[((size_t)tg * BB + b) * 256 + dir * HH + u] = bf16_rne(h);
            }
        }
        asm volatile("s_waitcnt lgkmcnt(0)" ::: "memory");
        __builtin_amdgcn_s_barrier();
        asm volatile("" ::: "memory");
        gin = gin_next;
    }
    if (q == 0) {
        h_state[sbase + u] = h;
        c_state[sbase + u] = c;
    }
}

// ---- FC head --------------------------------------------------------------
__global__ void fc_kernel(const float* __restrict__ h_state,  // (2,B,128)
                          const float* __restrict__ fc_w,     // (3,256)
                          const float* __restrict__ fc_b,     // (3,)
                          float* __restrict__ out) {          // (B,3)
    int tid = blockIdx.x * blockDim.x + threadIdx.x;
    if (tid >= BB * 3) return;
    int b = tid / 3;
    int c = tid % 3;
    float acc = 0.f;
    for (int j = 0; j < 256; ++j) {
        float v = (j < HH) ? h_state[((size_t)0 * BB + b) * HH + j]
                           : h_state[((size_t)1 * BB + b) * HH + (j - HH)];
        acc += v * fc_w[c * 256 + j];
    }
    out[b * 3 + c] = acc + fc_b[c];
}

extern "C" void kernel_launch(void* const* d_in, const int* in_sizes, int n_in,
                              void* d_out, int out_size, void* d_ws, size_t ws_size,
                              hipStream_t stream) {
    const int*   x        = (const int*)  d_in[0];
    const float* emb      = (const float*)d_in[1];
    const float* w_ih_l0  = (const float*)d_in[2];
    const float* w_hh_l0  = (const float*)d_in[3];
    const float* b_ih_l0  = (const float*)d_in[4];
    const float* b_hh_l0  = (const float*)d_in[5];
    const float* w_ih_l0r = (const float*)d_in[6];
    const float* w_hh_l0r = (const float*)d_in[7];
    const float* b_ih_l0r = (const float*)d_in[8];
    const float* b_hh_l0r = (const float*)d_in[9];
    const float* w_ih_l1  = (const float*)d_in[10];
    const float* w_hh_l1  = (const float*)d_in[11];
    const float* b_ih_l1  = (const float*)d_in[12];
    const float* b_hh_l1  = (const float*)d_in[13];
    const float* w_ih_l1r = (const float*)d_in[14];
    const float* w_hh_l1r = (const float*)d_in[15];
    const float* b_ih_l1r = (const float*)d_in[16];
    const float* b_hh_l1r = (const float*)d_in[17];
    const float* fc_w     = (const float*)d_in[18];
    const float* fc_b     = (const float*)d_in[19];
    float* out = (float*)d_out;
    (void)in_sizes; (void)n_in; (void)out_size;

    // ---- workspace layout ----
    size_t xs2_b   = (size_t)TT * BB * 128 * 2;         // 16.8 MB (bf16 hi)
    size_t x1_b    = (size_t)TT * BB * 256 * 2;         // 33.6 MB (bf16 hi)
    size_t w2l0_b  = (size_t)512 * 128 * 2;             // 128 KB
    size_t w2l1_b  = (size_t)512 * 256 * 2;             // 256 KB
    size_t bias_b  = (size_t)1024 * 4;                  // 4 KB
    size_t wpk_b   = (size_t)128 * 128 * 4 * 4;         // 256 KB each
    size_t state_b = (size_t)2 * BB * HH * 4;           // 128 KB
    size_t fixed = xs2_b + x1_b + 2 * w2l0_b + 2 * w2l1_b + 2 * bias_b
                 + 4 * wpk_b + 2 * state_b + 4096;
    int TC = 512;
    while (TC > 8) {
        size_t chunk2 = (size_t)TC * BB * G4 * 4 * 2;
        if (fixed + chunk2 <= ws_size) break;
        TC >>= 1;
    }
    char* ws = (char*)d_ws;
    size_t off = 0;
    unsigned short* xs2   = (unsigned short*)(ws + off); off += xs2_b;
    unsigned short* x1_2  = (unsigned short*)(ws + off); off += x1_b;
    unsigned short* w2l0f = (unsigned short*)(ws + off); off += w2l0_b;   // cat: fwd..
    unsigned short* w2l0r = (unsigned short*)(ws + off); off += w2l0_b;   // ..bwd
    unsigned short* w2l1f = (unsigned short*)(ws + off); off += w2l1_b;
    unsigned short* w2l1r = (unsigned short*)(ws + off); off += w2l1_b;
    float* biasl0  = (float*)(ws + off); off += bias_b;
    float* biasl1  = (float*)(ws + off); off += bias_b;
    float* wpk0f   = (float*)(ws + off); off += wpk_b;
    float* wpk0r   = (float*)(ws + off); off += wpk_b;
    float* wpk1f   = (float*)(ws + off); off += wpk_b;
    float* wpk1r   = (float*)(ws + off); off += wpk_b;
    float* h_state = (float*)(ws + off); off += state_b;
    float* c_state = (float*)(ws + off); off += state_b;
    float* gxf     = (float*)(ws + off); off += (size_t)TC * BB * G4 * 4;
    float* gxr     = (float*)(ws + off);

    int NC = TT / TC;
    dim3 ggrid(8, TC);

    // ---- precompute packed/bf16 forms ----
    embed_cvt<<<TT * BB, 128, 0, stream>>>(x, emb, xs2);
    wcvt<<<512, 128, 0, stream>>>(w_ih_l0,  EE, 128, w2l0f);
    wcvt<<<512, 128, 0, stream>>>(w_ih_l0r, EE, 128, w2l0r);
    wcvt<<<512, 256, 0, stream>>>(w_ih_l1,  K1, 256, w2l1f);
    wcvt<<<512, 256, 0, stream>>>(w_ih_l1r, K1, 256, w2l1r);
    bias_cat<<<4, 256, 0, stream>>>(b_ih_l0, b_hh_l0, b_ih_l0r, b_hh_l0r, biasl0);
    bias_cat<<<4, 256, 0, stream>>>(b_ih_l1, b_hh_l1, b_ih_l1r, b_hh_l1r, biasl1);
    whh_pack<<<128, 128, 0, stream>>>(w_hh_l0,  wpk0f);
    whh_pack<<<128, 128, 0, stream>>>(w_hh_l0r, wpk0r);
    whh_pack<<<128, 128, 0, stream>>>(w_hh_l1,  wpk1f);
    whh_pack<<<128, 128, 0, stream>>>(w_hh_l1r, wpk1r);

    // ---- layer 0 ----
    hipMemsetAsync(h_state, 0, state_b, stream);
    hipMemsetAsync(c_state, 0, state_b, stream);
    for (int ci = 0; ci < NC; ++ci) {
        int t0 = ci * TC;
        gemm_mfma<128><<<ggrid, 256, 0, stream>>>(xs2, w2l0f, biasl0, gxf, gxr, t0);
        lstm_chunk<<<256, 512, 0, stream>>>(gxf, gxr, wpk0f, wpk0r,
                                            h_state, c_state, x1_2, t0, TC);
    }
    // ---- layer 1 ----
    hipMemsetAsync(h_state, 0, state_b, stream);
    hipMemsetAsync(c_state, 0, state_b, stream);
    for (int ci = 0; ci < NC; ++ci) {
        int t0 = ci * TC;
        gemm_mfma<256><<<ggrid, 256, 0, stream>>>(x1_2, w2l1f, biasl1, gxf, gxr, t0);
        lstm_chunk<<<256, 512, 0, stream>>>(gxf, gxr, wpk1f, wpk1r,
                                            h_state, c_state, nullptr, t0, TC);
    }
    // ---- FC head ----
    fc_kernel<<<2, 192, 0, stream>>>(h_state, fc_w, fc_b, out);
}